// Round 2
// baseline (210.446 us; speedup 1.0000x reference)
//
#include <hip/hip_runtime.h>

typedef __attribute__((ext_vector_type(8))) short short8;
typedef __attribute__((ext_vector_type(4))) float floatx4;

#define CIN    192
#define COUTN  192
#define HWDIM  56
#define HWSZ   (56*56)
#define KWT    1728
#define TH     4
#define HY     6
#define PH     58
#define CK     32
#define NCHUNK 6
#define MT     64

// ws layout: xpack [b 32][cc 6][h' 58][x' 58][c 32] bf16 (chunk-swizzled within pixel);
//            wpack [og 3][cc 6][off 9][m 64][c 32] bf16
// Chunk swizzle: pixel P = h'*58 + x' holds 4x 16B chunks; logical channel-group g is
// stored at slot  g ^ ((P>>1)&3).  Consistent across conv tiles since gh0*58 % 8 == 0.
#define XPACK_SHORTS (32u*6u*58u*58u*32u)   /* 20,668,416 shorts = 41,336,832 B */
#define WPACK_SHORTS (3u*6u*9u*64u*32u)     /* 331,776 shorts = 663,552 B */
#define WS_NEEDED    ((size_t)(XPACK_SHORTS + WPACK_SHORTS) * 2u)

__device__ __forceinline__ short f2bf(float f) {
    union { float f; unsigned u; } v; v.f = f;
    unsigned u = v.u + 0x7FFFu + ((v.u >> 16) & 1u);  // RNE
    return (short)(u >> 16);
}

// pack two floats (lo=even channel, hi=odd channel) into one uint of 2x bf16, RNE
__device__ __forceinline__ unsigned pk2(float lo, float hi) {
    union { float f; unsigned u; } a, b;
    a.f = lo; b.f = hi;
    unsigned ua = a.u + 0x7FFFu + ((a.u >> 16) & 1u);
    unsigned ub = b.u + 0x7FFFu + ((b.u >> 16) & 1u);
    return (ua >> 16) | (ub & 0xFFFF0000u);
}

// ---------------- pre-pass: pack x to padded NHWC-chunked bf16 (LDS transpose) ----------------
#define XP_P 788   /* padded pitch (uints); 784 pixels + 4 pad -> <=2-way bank alias on reads */

__global__ __launch_bounds__(256)
void pack_x(const float* __restrict__ x, short* __restrict__ xp) {
    __shared__ unsigned sp[16 * XP_P];                  // 50,432 B
    const int tid = threadIdx.x;
    const int bid = blockIdx.x;                         // b*24 + cc*4 + rg
    const int rg  = bid & 3;
    const int cc  = (bid >> 2) % 6;
    const int b   = bid / 24;
    const int h0  = rg * 14;                            // first input row of this group

    // ---- phase 1: global (coalesced) -> LDS, NCHW fp32 -> pair-interleaved bf16 ----
    const float* base = x + ((size_t)(b * CIN + cc * 32) * HWSZ + (size_t)h0 * HWDIM);
    for (int i = tid; i < 16 * 196; i += 256) {         // 16 channel pairs x 196 float4s
        int a = i / 196;                                // channel pair
        int j = i - a * 196;                            // float4 index within 784 pixels
        const float4 f0 = *(const float4*)(base + (size_t)(2 * a)     * HWSZ + j * 4);
        const float4 f1 = *(const float4*)(base + (size_t)(2 * a + 1) * HWSZ + j * 4);
        uint4 u;
        u.x = pk2(f0.x, f1.x);
        u.y = pk2(f0.y, f1.y);
        u.z = pk2(f0.z, f1.z);
        u.w = pk2(f0.w, f1.w);
        *(uint4*)&sp[a * XP_P + j * 4] = u;             // ds_write_b128, conflict-free
    }
    __syncthreads();

    // ---- phase 2: LDS -> global, [pair][pixel] -> [h'][x'][c] with zero x-borders ----
    // chunk slot within pixel is swizzled: s = g ^ ((P>>1)&3), P = padded pixel index
    short* orow = xp + (((size_t)(b * 6 + cc) * PH + (h0 + 1)) * PH) * CK;
    for (int i = tid; i < 14 * 58 * 4; i += 256) {      // 3248 short8 stores
        int g  = i & 3;                                 // logical channel group of 8
        int t  = i >> 2;
        int xq = t % 58;
        int r  = t / 58;                                // local row 0..13
        uint4 u = (uint4){0u, 0u, 0u, 0u};
        if (xq > 0 && xq < 57) {
            int w = r * 56 + xq - 1;
            u.x = sp[(4 * g + 0) * XP_P + w];
            u.y = sp[(4 * g + 1) * XP_P + w];
            u.z = sp[(4 * g + 2) * XP_P + w];
            u.w = sp[(4 * g + 3) * XP_P + w];
        }
        int P = (h0 + 1 + r) * PH + xq;                 // padded-global pixel index
        int s = g ^ ((P >> 1) & 3);                     // swizzled chunk slot
        *(uint4*)(orow + ((size_t)r * PH + xq) * CK + s * 8) = u;
    }

    // ---- zero pad rows h'=0 (rg==0) and h'=57 (rg==3) ---- (all-zero: swizzle irrelevant)
    if (rg == 0 || rg == 3) {
        int hq = (rg == 0) ? 0 : 57;
        short* prow = xp + (((size_t)(b * 6 + cc) * PH + hq) * PH) * CK;
        for (int i = tid; i < 58 * 4; i += 256)
            *(uint4*)(prow + (size_t)i * 8) = (uint4){0u, 0u, 0u, 0u};
    }
}

// ---------------- pre-pass: pack weights to [og][cc][off][m][c] bf16 ----------------
__global__ __launch_bounds__(256)
void pack_w(const float* __restrict__ w, short* __restrict__ wp) {
    int idx = blockIdx.x * 256 + threadIdx.x;          // one thread per 16B chunk
    const int TOT = 3 * 6 * 9 * 64 * 4;
    if (idx >= TOT) return;
    int cg = idx & 3;
    int m  = (idx >> 2) & 63;
    int t  = idx >> 8;                                  // og*54 + cc*9 + off
    int off = t % 9;  t /= 9;
    int cc  = t % 6;
    int og  = t / 6;
    short8 v;
#pragma unroll
    for (int k = 0; k < 8; ++k)
        v[k] = f2bf(w[(size_t)(og * 64 + m) * KWT + (cc * 32 + cg * 8 + k) * 9 + off]);
    *(short8*)(wp + (size_t)idx * 8) = v;
}

// ---------------- main: implicit-GEMM conv, halo via global_load_lds ----------------
// 1D grid 1344: bid -> xcd = bid&7 (XCD round-robin); 3 og-partner blocks that share an
// xp tile are consecutive slots on the SAME XCD -> L2-hit for the 2nd/3rd stage.
// Launched with 19 KB dynamic LDS to cap residency at 3 blocks/CU (tail: 1344/768=1.75
// rounds ~87.5% fill, vs 4/CU giving 1344/1024=1.31 rounds ~66% fill).
__global__ __launch_bounds__(256, 2)
void conv_main(const short* __restrict__ xp, const short* __restrict__ wp,
               const float* __restrict__ bias, float* __restrict__ out) {
    __shared__ __align__(16) short sh[HY * PH * CK];    // 22,272 B static

    const int tid  = threadIdx.x;
    const int u    = blockIdx.x;                        // 0..1343
    const int xcd  = u & 7;
    const int slot = u >> 3;                            // 0..167
    const int og   = slot % 3;
    const int tile = xcd * 56 + slot / 3;               // 0..447
    const int bx   = tile % 14;
    const int bb   = tile / 14;
    const int gh0  = bx * TH;
    const int lane = tid & 63;
    const int wave = tid >> 6;
    const int wm   = wave >> 1;
    const int wn   = wave & 1;
    const int g    = lane >> 4;
    const int col  = lane & 15;

    int ly[7], lx[7], pnt[7];
#pragma unroll
    for (int nt = 0; nt < 7; ++nt) {
        int l = wn * 112 + nt * 16 + col;
        ly[nt] = l / 56;
        lx[nt] = l % 56;
        pnt[nt] = ly[nt] * PH + lx[nt];                 // tile-local pixel index
    }

    floatx4 acc[2][7];
#pragma unroll
    for (int mt = 0; mt < 2; ++mt)
#pragma unroll
        for (int nt = 0; nt < 7; ++nt)
            acc[mt][nt] = (floatx4){0.f, 0.f, 0.f, 0.f};

    const short8* wpk = (const short8*)wp;
    const int wlbase = wave * 64;                       // wave-uniform lds chunk base

    for (int cc = 0; cc < NCHUNK; ++cc) {
        if (cc) __syncthreads();                        // all waves done reading prev tile

        // stage halo: one contiguous 22,272 B region, lane-linear -> global_load_lds x16B
        const short* src = xp + ((size_t)(bb * 6 + cc) * (PH * PH) + (size_t)gh0 * PH) * CK;
#pragma unroll
        for (int j = 0; j < 6; ++j) {
            int idx = j * 256 + tid;
            if (idx < HY * PH * 4) {                    // 1392 chunks
                __builtin_amdgcn_global_load_lds(
                    (const __attribute__((address_space(1))) void*)(src + (size_t)idx * 8),
                    (__attribute__((address_space(3))) void*)(sh + (j * 256 + wlbase) * 8),
                    16, 0, 0);
            }
        }

        // a-frags to registers (coalesced L2-hit dwordx4); drained by the barrier's vmcnt(0)
        short8 afr[9][2];
#pragma unroll
        for (int off = 0; off < 9; ++off)
#pragma unroll
            for (int mt = 0; mt < 2; ++mt)
                afr[off][mt] = wpk[((og * 6 + cc) * 9 + off) * 256 + (wm * 32 + mt * 16 + col) * 4 + g];

        __syncthreads();

#pragma unroll
        for (int off = 0; off < 9; ++off) {
            const int doff = (off / 3) * PH + (off % 3);
#pragma unroll
            for (int nt = 0; nt < 7; ++nt) {
                int p = pnt[nt] + doff;                 // tile-local pixel (== global mod 8)
                int s = ((p >> 1) & 3) ^ g;             // de-swizzled chunk slot
                short8 bfr = *(const short8*)&sh[(p << 5) + (s << 3)];
                acc[0][nt] = __builtin_amdgcn_mfma_f32_16x16x32_bf16(afr[off][0], bfr, acc[0][nt], 0, 0, 0);
                acc[1][nt] = __builtin_amdgcn_mfma_f32_16x16x32_bf16(afr[off][1], bfr, acc[1][nt], 0, 0, 0);
            }
        }
    }

    // epilogue: D row = g*4 + r, col = lane&15
#pragma unroll
    for (int mt = 0; mt < 2; ++mt) {
        int o = og * 64 + wm * 32 + mt * 16 + g * 4;
#pragma unroll
        for (int nt = 0; nt < 7; ++nt) {
            int l  = wn * 112 + nt * 16 + col;
            int h  = gh0 + l / 56;
            int ww = l % 56;
            size_t base = ((size_t)(bb * COUTN + o) * HWDIM + h) * HWDIM + ww;
            floatx4 v = acc[mt][nt];
#pragma unroll
            for (int r2 = 0; r2 < 4; ++r2)
                out[base + (size_t)r2 * HWSZ] = v[r2] + bias[o + r2];
        }
    }
}

// ---------------- fallback (round-1 kernel) if ws too small ----------------
__global__ __launch_bounds__(256, 2)
void conv3x3_fb(const float* __restrict__ x, const float* __restrict__ w,
                const float* __restrict__ bias, float* __restrict__ out) {
    __shared__ __align__(16) short sh_halo[HY * PH * CK];
    __shared__ __align__(16) short sh_w[9 * MT * CK];
    const int tid = threadIdx.x;
    const int gh0 = blockIdx.x * TH;
    const int o0  = blockIdx.y * MT;
    const int bb  = blockIdx.z;
    const int lane = tid & 63, wave = tid >> 6;
    const int wm = wave >> 1, wn = wave & 1;
    const int g = lane >> 4, col = lane & 15;
    int ly[7], lx[7];
#pragma unroll
    for (int nt = 0; nt < 7; ++nt) {
        int l = wn * 112 + nt * 16 + col;
        ly[nt] = l / 56; lx[nt] = l % 56;
    }
    floatx4 acc[2][7];
#pragma unroll
    for (int mt = 0; mt < 2; ++mt)
#pragma unroll
        for (int nt = 0; nt < 7; ++nt) acc[mt][nt] = (floatx4){0.f,0.f,0.f,0.f};
    for (int cc = 0; cc < NCHUNK; ++cc) {
        const int c0 = cc * CK;
        if (cc) __syncthreads();
        for (int i = tid; i < 4 * HY * PH; i += 256) {
            int xx = i % PH, r = i / PH, y = r % HY, cg = r / HY;
            int gh = gh0 + y - 1, gw = xx - 1;
            bool ok = ((unsigned)gh < 56u) & ((unsigned)gw < 56u);
            const float* src = x + ((size_t)(bb * CIN + c0 + cg * 8) * HWDIM + gh) * HWDIM + gw;
            short8 v;
#pragma unroll
            for (int k = 0; k < 8; ++k) v[k] = f2bf(ok ? src[k * HWSZ] : 0.f);
            *(short8*)&sh_halo[(y * PH + xx) * CK + ((cg ^ ((xx >> 1) & 3)) << 3)] = v;
        }
        for (int i = tid; i < 9 * MT * 4; i += 256) {
            int cg = i & 3, off = (i >> 2) % 9, m = i / 36;
            const float* src = w + (size_t)(o0 + m) * KWT + (c0 + cg * 8) * 9 + off;
            short8 v;
#pragma unroll
            for (int k = 0; k < 8; ++k) v[k] = f2bf(src[k * 9]);
            *(short8*)&sh_w[(off * MT + m) * CK + ((cg ^ ((m >> 1) & 3)) << 3)] = v;
        }
        __syncthreads();
#pragma unroll
        for (int off = 0; off < 9; ++off) {
            const int di = off / 3, dj = off % 3;
            short8 a[2];
#pragma unroll
            for (int mt = 0; mt < 2; ++mt) {
                int m = wm * 32 + mt * 16 + col;
                a[mt] = *(const short8*)&sh_w[(off * MT + m) * CK + ((g ^ ((m >> 1) & 3)) << 3)];
            }
#pragma unroll
            for (int nt = 0; nt < 7; ++nt) {
                int yy = ly[nt] + di, xpp = lx[nt] + dj;
                short8 bfr = *(const short8*)&sh_halo[(yy * PH + xpp) * CK + ((g ^ ((xpp >> 1) & 3)) << 3)];
                acc[0][nt] = __builtin_amdgcn_mfma_f32_16x16x32_bf16(a[0], bfr, acc[0][nt], 0, 0, 0);
                acc[1][nt] = __builtin_amdgcn_mfma_f32_16x16x32_bf16(a[1], bfr, acc[1][nt], 0, 0, 0);
            }
        }
    }
#pragma unroll
    for (int mt = 0; mt < 2; ++mt) {
        int o = o0 + wm * 32 + mt * 16 + g * 4;
#pragma unroll
        for (int nt = 0; nt < 7; ++nt) {
            int l = wn * 112 + nt * 16 + col;
            int h = gh0 + l / 56, ww = l % 56;
            size_t base = ((size_t)(bb * COUTN + o) * HWDIM + h) * HWDIM + ww;
            floatx4 v = acc[mt][nt];
#pragma unroll
            for (int r2 = 0; r2 < 4; ++r2)
                out[base + (size_t)r2 * HWSZ] = v[r2] + bias[o + r2];
        }
    }
}

extern "C" void kernel_launch(void* const* d_in, const int* in_sizes, int n_in,
                              void* d_out, int out_size, void* d_ws, size_t ws_size,
                              hipStream_t stream) {
    const float* x  = (const float*)d_in[0];
    const float* wt = (const float*)d_in[1];
    const float* bi = (const float*)d_in[2];
    float* out = (float*)d_out;

    if (ws_size >= WS_NEEDED) {
        short* xpk = (short*)d_ws;
        short* wpk = xpk + XPACK_SHORTS;
        pack_x<<<32 * 6 * 4, 256, 0, stream>>>(x, xpk);
        {
            int tot = 3 * 6 * 9 * 64 * 4;
            pack_w<<<(tot + 255) / 256, 256, 0, stream>>>(wt, wpk);
        }
        // 19 KB dynamic LDS (unused) caps residency at 3 blocks/CU (22.3+19 KB > 160/4)
        conv_main<<<dim3(14 * 3 * 32), dim3(256), 19456, stream>>>(xpk, wpk, bi, out);
    } else {
        conv3x3_fb<<<dim3(14, 3, 32), dim3(256), 0, stream>>>(x, wt, bi, out);
    }
}

// Round 3
// 207.445 us; speedup vs baseline: 1.0145x; 1.0145x over previous
//
#include <hip/hip_runtime.h>

typedef __attribute__((ext_vector_type(8))) short short8;
typedef __attribute__((ext_vector_type(4))) float floatx4;

#define CIN    192
#define COUTN  192
#define HWDIM  56
#define HWSZ   (56*56)
#define KWT    1728
#define TH     4
#define HY     6
#define PH     58
#define CK     32
#define NCHUNK 6
#define MT     64

// ws layout: xpack [b 32][cc 6][h' 58][x' 58][c 32] bf16 (chunk-swizzled within pixel);
//            wpack [og 3][cc 6][off 9][m 64][c 32] bf16
// Chunk swizzle: pixel P = h'*58 + x' holds 4x 16B chunks; logical channel-group g is
// stored at slot  g ^ ((P>>1)&3).  Consistent across conv tiles since gh0*58 % 8 == 0.
#define XPACK_SHORTS (32u*6u*58u*58u*32u)   /* 20,668,416 shorts = 41,336,832 B */
#define WPACK_SHORTS (3u*6u*9u*64u*32u)     /* 331,776 shorts = 663,552 B */
#define WS_NEEDED    ((size_t)(XPACK_SHORTS + WPACK_SHORTS) * 2u)

__device__ __forceinline__ short f2bf(float f) {
    union { float f; unsigned u; } v; v.f = f;
    unsigned u = v.u + 0x7FFFu + ((v.u >> 16) & 1u);  // RNE
    return (short)(u >> 16);
}

// pack two floats (lo=even channel, hi=odd channel) into one uint of 2x bf16, RNE
__device__ __forceinline__ unsigned pk2(float lo, float hi) {
    union { float f; unsigned u; } a, b;
    a.f = lo; b.f = hi;
    unsigned ua = a.u + 0x7FFFu + ((a.u >> 16) & 1u);
    unsigned ub = b.u + 0x7FFFu + ((b.u >> 16) & 1u);
    return (ua >> 16) | (ub & 0xFFFF0000u);
}

// ---------------- pre-pass: pack x to padded NHWC-chunked bf16 (LDS transpose) ----------------
#define XP_P 788   /* padded pitch (uints); 784 pixels + 4 pad -> <=2-way bank alias on reads */

__global__ __launch_bounds__(256)
void pack_x(const float* __restrict__ x, short* __restrict__ xp) {
    __shared__ unsigned sp[16 * XP_P];                  // 50,432 B
    const int tid = threadIdx.x;
    const int bid = blockIdx.x;                         // b*24 + cc*4 + rg
    const int rg  = bid & 3;
    const int cc  = (bid >> 2) % 6;
    const int b   = bid / 24;
    const int h0  = rg * 14;                            // first input row of this group

    // ---- phase 1: global (coalesced) -> LDS, NCHW fp32 -> pair-interleaved bf16 ----
    const float* base = x + ((size_t)(b * CIN + cc * 32) * HWSZ + (size_t)h0 * HWDIM);
    for (int i = tid; i < 16 * 196; i += 256) {         // 16 channel pairs x 196 float4s
        int a = i / 196;                                // channel pair
        int j = i - a * 196;                            // float4 index within 784 pixels
        const float4 f0 = *(const float4*)(base + (size_t)(2 * a)     * HWSZ + j * 4);
        const float4 f1 = *(const float4*)(base + (size_t)(2 * a + 1) * HWSZ + j * 4);
        uint4 u;
        u.x = pk2(f0.x, f1.x);
        u.y = pk2(f0.y, f1.y);
        u.z = pk2(f0.z, f1.z);
        u.w = pk2(f0.w, f1.w);
        *(uint4*)&sp[a * XP_P + j * 4] = u;             // ds_write_b128, conflict-free
    }
    __syncthreads();

    // ---- phase 2: LDS -> global, [pair][pixel] -> [h'][x'][c] with zero x-borders ----
    // chunk slot within pixel is swizzled: s = g ^ ((P>>1)&3), P = padded pixel index
    short* orow = xp + (((size_t)(b * 6 + cc) * PH + (h0 + 1)) * PH) * CK;
    for (int i = tid; i < 14 * 58 * 4; i += 256) {      // 3248 short8 stores
        int g  = i & 3;                                 // logical channel group of 8
        int t  = i >> 2;
        int xq = t % 58;
        int r  = t / 58;                                // local row 0..13
        uint4 u = (uint4){0u, 0u, 0u, 0u};
        if (xq > 0 && xq < 57) {
            int w = r * 56 + xq - 1;
            u.x = sp[(4 * g + 0) * XP_P + w];
            u.y = sp[(4 * g + 1) * XP_P + w];
            u.z = sp[(4 * g + 2) * XP_P + w];
            u.w = sp[(4 * g + 3) * XP_P + w];
        }
        int P = (h0 + 1 + r) * PH + xq;                 // padded-global pixel index
        int s = g ^ ((P >> 1) & 3);                     // swizzled chunk slot
        *(uint4*)(orow + ((size_t)r * PH + xq) * CK + s * 8) = u;
    }

    // ---- zero pad rows h'=0 (rg==0) and h'=57 (rg==3) ---- (all-zero: swizzle irrelevant)
    if (rg == 0 || rg == 3) {
        int hq = (rg == 0) ? 0 : 57;
        short* prow = xp + (((size_t)(b * 6 + cc) * PH + hq) * PH) * CK;
        for (int i = tid; i < 58 * 4; i += 256)
            *(uint4*)(prow + (size_t)i * 8) = (uint4){0u, 0u, 0u, 0u};
    }
}

// ---------------- pre-pass: pack weights to [og][cc][off][m][c] bf16 ----------------
__global__ __launch_bounds__(256)
void pack_w(const float* __restrict__ w, short* __restrict__ wp) {
    int idx = blockIdx.x * 256 + threadIdx.x;          // one thread per 16B chunk
    const int TOT = 3 * 6 * 9 * 64 * 4;
    if (idx >= TOT) return;
    int cg = idx & 3;
    int m  = (idx >> 2) & 63;
    int t  = idx >> 8;                                  // og*54 + cc*9 + off
    int off = t % 9;  t /= 9;
    int cc  = t % 6;
    int og  = t / 6;
    short8 v;
#pragma unroll
    for (int k = 0; k < 8; ++k)
        v[k] = f2bf(w[(size_t)(og * 64 + m) * KWT + (cc * 32 + cg * 8 + k) * 9 + off]);
    *(short8*)(wp + (size_t)idx * 8) = v;
}

// ---------------- main: implicit-GEMM conv, halo via global_load_lds ----------------
// 1D grid 1344: bid -> xcd = bid&7 (XCD round-robin); 3 og-partner blocks that share an
// xp tile are consecutive slots on the SAME XCD -> L2-hit for the 2nd/3rd stage.
// NO residency cap: 4 blocks/CU (VGPR-limited) is required for the cross-block wave
// overlap that hides the per-chunk vmcnt(0) barrier drain (round-2 post-mortem: capping
// at 3/CU cost +15 us despite better tail fill).
__global__ __launch_bounds__(256, 2)
void conv_main(const short* __restrict__ xp, const short* __restrict__ wp,
               const float* __restrict__ bias, float* __restrict__ out) {
    __shared__ __align__(16) short sh[HY * PH * CK];    // 22,272 B

    const int tid  = threadIdx.x;
    const int u    = blockIdx.x;                        // 0..1343
    const int xcd  = u & 7;
    const int slot = u >> 3;                            // 0..167
    const int og   = slot % 3;
    const int tile = xcd * 56 + slot / 3;               // 0..447
    const int bx   = tile % 14;
    const int bb   = tile / 14;
    const int gh0  = bx * TH;
    const int lane = tid & 63;
    const int wave = tid >> 6;
    const int wm   = wave >> 1;
    const int wn   = wave & 1;
    const int g    = lane >> 4;
    const int col  = lane & 15;

    int ly[7], lx[7], pnt[7];
#pragma unroll
    for (int nt = 0; nt < 7; ++nt) {
        int l = wn * 112 + nt * 16 + col;
        ly[nt] = l / 56;
        lx[nt] = l % 56;
        pnt[nt] = ly[nt] * PH + lx[nt];                 // tile-local pixel index
    }

    floatx4 acc[2][7];
#pragma unroll
    for (int mt = 0; mt < 2; ++mt)
#pragma unroll
        for (int nt = 0; nt < 7; ++nt)
            acc[mt][nt] = (floatx4){0.f, 0.f, 0.f, 0.f};

    const short8* wpk = (const short8*)wp;
    const int wlbase = wave * 64;                       // wave-uniform lds chunk base

    for (int cc = 0; cc < NCHUNK; ++cc) {
        if (cc) __syncthreads();                        // all waves done reading prev tile

        // stage halo: one contiguous 22,272 B region, lane-linear -> global_load_lds x16B
        const short* src = xp + ((size_t)(bb * 6 + cc) * (PH * PH) + (size_t)gh0 * PH) * CK;
#pragma unroll
        for (int j = 0; j < 6; ++j) {
            int idx = j * 256 + tid;
            if (idx < HY * PH * 4) {                    // 1392 chunks
                __builtin_amdgcn_global_load_lds(
                    (const __attribute__((address_space(1))) void*)(src + (size_t)idx * 8),
                    (__attribute__((address_space(3))) void*)(sh + (j * 256 + wlbase) * 8),
                    16, 0, 0);
            }
        }

        // a-frags to registers (coalesced L2-hit dwordx4); drained by the barrier's vmcnt(0)
        short8 afr[9][2];
#pragma unroll
        for (int off = 0; off < 9; ++off)
#pragma unroll
            for (int mt = 0; mt < 2; ++mt)
                afr[off][mt] = wpk[((og * 6 + cc) * 9 + off) * 256 + (wm * 32 + mt * 16 + col) * 4 + g];

        __syncthreads();

#pragma unroll
        for (int off = 0; off < 9; ++off) {
            const int doff = (off / 3) * PH + (off % 3);
#pragma unroll
            for (int nt = 0; nt < 7; ++nt) {
                int p = pnt[nt] + doff;                 // tile-local pixel (== global mod 8)
                int s = ((p >> 1) & 3) ^ g;             // de-swizzled chunk slot
                short8 bfr = *(const short8*)&sh[(p << 5) + (s << 3)];
                acc[0][nt] = __builtin_amdgcn_mfma_f32_16x16x32_bf16(afr[off][0], bfr, acc[0][nt], 0, 0, 0);
                acc[1][nt] = __builtin_amdgcn_mfma_f32_16x16x32_bf16(afr[off][1], bfr, acc[1][nt], 0, 0, 0);
            }
        }
    }

    // epilogue: D row = g*4 + r, col = lane&15
#pragma unroll
    for (int mt = 0; mt < 2; ++mt) {
        int o = og * 64 + wm * 32 + mt * 16 + g * 4;
#pragma unroll
        for (int nt = 0; nt < 7; ++nt) {
            int l  = wn * 112 + nt * 16 + col;
            int h  = gh0 + l / 56;
            int ww = l % 56;
            size_t base = ((size_t)(bb * COUTN + o) * HWDIM + h) * HWDIM + ww;
            floatx4 v = acc[mt][nt];
#pragma unroll
            for (int r2 = 0; r2 < 4; ++r2)
                out[base + (size_t)r2 * HWSZ] = v[r2] + bias[o + r2];
        }
    }
}

// ---------------- fallback (round-1 kernel) if ws too small ----------------
__global__ __launch_bounds__(256, 2)
void conv3x3_fb(const float* __restrict__ x, const float* __restrict__ w,
                const float* __restrict__ bias, float* __restrict__ out) {
    __shared__ __align__(16) short sh_halo[HY * PH * CK];
    __shared__ __align__(16) short sh_w[9 * MT * CK];
    const int tid = threadIdx.x;
    const int gh0 = blockIdx.x * TH;
    const int o0  = blockIdx.y * MT;
    const int bb  = blockIdx.z;
    const int lane = tid & 63, wave = tid >> 6;
    const int wm = wave >> 1, wn = wave & 1;
    const int g = lane >> 4, col = lane & 15;
    int ly[7], lx[7];
#pragma unroll
    for (int nt = 0; nt < 7; ++nt) {
        int l = wn * 112 + nt * 16 + col;
        ly[nt] = l / 56; lx[nt] = l % 56;
    }
    floatx4 acc[2][7];
#pragma unroll
    for (int mt = 0; mt < 2; ++mt)
#pragma unroll
        for (int nt = 0; nt < 7; ++nt) acc[mt][nt] = (floatx4){0.f,0.f,0.f,0.f};
    for (int cc = 0; cc < NCHUNK; ++cc) {
        const int c0 = cc * CK;
        if (cc) __syncthreads();
        for (int i = tid; i < 4 * HY * PH; i += 256) {
            int xx = i % PH, r = i / PH, y = r % HY, cg = r / HY;
            int gh = gh0 + y - 1, gw = xx - 1;
            bool ok = ((unsigned)gh < 56u) & ((unsigned)gw < 56u);
            const float* src = x + ((size_t)(bb * CIN + c0 + cg * 8) * HWDIM + gh) * HWDIM + gw;
            short8 v;
#pragma unroll
            for (int k = 0; k < 8; ++k) v[k] = f2bf(ok ? src[k * HWSZ] : 0.f);
            *(short8*)&sh_halo[(y * PH + xx) * CK + ((cg ^ ((xx >> 1) & 3)) << 3)] = v;
        }
        for (int i = tid; i < 9 * MT * 4; i += 256) {
            int cg = i & 3, off = (i >> 2) % 9, m = i / 36;
            const float* src = w + (size_t)(o0 + m) * KWT + (c0 + cg * 8) * 9 + off;
            short8 v;
#pragma unroll
            for (int k = 0; k < 8; ++k) v[k] = f2bf(src[k * 9]);
            *(short8*)&sh_w[(off * MT + m) * CK + ((cg ^ ((m >> 1) & 3)) << 3)] = v;
        }
        __syncthreads();
#pragma unroll
        for (int off = 0; off < 9; ++off) {
            const int di = off / 3, dj = off % 3;
            short8 a[2];
#pragma unroll
            for (int mt = 0; mt < 2; ++mt) {
                int m = wm * 32 + mt * 16 + col;
                a[mt] = *(const short8*)&sh_w[(off * MT + m) * CK + ((g ^ ((m >> 1) & 3)) << 3)];
            }
#pragma unroll
            for (int nt = 0; nt < 7; ++nt) {
                int yy = ly[nt] + di, xpp = lx[nt] + dj;
                short8 bfr = *(const short8*)&sh_halo[(yy * PH + xpp) * CK + ((g ^ ((xpp >> 1) & 3)) << 3)];
                acc[0][nt] = __builtin_amdgcn_mfma_f32_16x16x32_bf16(a[0], bfr, acc[0][nt], 0, 0, 0);
                acc[1][nt] = __builtin_amdgcn_mfma_f32_16x16x32_bf16(a[1], bfr, acc[1][nt], 0, 0, 0);
            }
        }
    }
#pragma unroll
    for (int mt = 0; mt < 2; ++mt) {
        int o = o0 + wm * 32 + mt * 16 + g * 4;
#pragma unroll
        for (int nt = 0; nt < 7; ++nt) {
            int l = wn * 112 + nt * 16 + col;
            int h = gh0 + l / 56, ww = l % 56;
            size_t base = ((size_t)(bb * COUTN + o) * HWDIM + h) * HWDIM + ww;
            floatx4 v = acc[mt][nt];
#pragma unroll
            for (int r2 = 0; r2 < 4; ++r2)
                out[base + (size_t)r2 * HWSZ] = v[r2] + bias[o + r2];
        }
    }
}

extern "C" void kernel_launch(void* const* d_in, const int* in_sizes, int n_in,
                              void* d_out, int out_size, void* d_ws, size_t ws_size,
                              hipStream_t stream) {
    const float* x  = (const float*)d_in[0];
    const float* wt = (const float*)d_in[1];
    const float* bi = (const float*)d_in[2];
    float* out = (float*)d_out;

    if (ws_size >= WS_NEEDED) {
        short* xpk = (short*)d_ws;
        short* wpk = xpk + XPACK_SHORTS;
        pack_x<<<32 * 6 * 4, 256, 0, stream>>>(x, xpk);
        {
            int tot = 3 * 6 * 9 * 64 * 4;
            pack_w<<<(tot + 255) / 256, 256, 0, stream>>>(wt, wpk);
        }
        conv_main<<<dim3(14 * 3 * 32), dim3(256), 0, stream>>>(xpk, wpk, bi, out);
    } else {
        conv3x3_fb<<<dim3(14, 3, 32), dim3(256), 0, stream>>>(x, wt, bi, out);
    }
}